// Round 1
// baseline (157.353 us; speedup 1.0000x reference)
//
#include <hip/hip_runtime.h>

// out[i] = gen_map[x_gen[i]] + c * x_max_clock_speed[i] + d * x_max_tdp[i]
// N = 8388608 (2^23), NUM_GENS = 1024.
// Ledger: R1 46, R2 44, R4 42 (nt stores +5%), R5 38 (nt loads +10%),
// R6 37 (pipeline depth: neutral), R7 39 (regular stores: regression),
// R8 ~37 (contiguous chunks + XCD swizzle: neutral).
// Model: per-CU outstanding-read-miss cap. Read-side 10.6 GB/s/CU vs copy
// bench's 12.3 GB/s/CU -> floor ~32us for this 3r:1w mix. Writes are free
// (fill kernel does 6.6 TB/s write-only).
// R9 (this round): attack the 14% gap to the read ceiling via per-wave
// serialization, not depth:
//   (a) per-wave private 4KB table copy -> NO __syncthreads, no
//       vmcnt(0)+lgkmcnt(0) barrier drain, waves fully decoupled;
//   (b) table loads issued FIRST (oldest in queue) so the ds_write wait is
//       vmcnt(12), not a full drain — streaming loads enter the queue at t=0;
//   (c) streaming loads interleaved PER STAGE (g_i,a_i,b_i adjacent) so
//       stage i completes after 3(i+1) in-order returns instead of 9+i ->
//       earlier compute + earlier nt-store overlap with remaining returns.

#define NUM_GENS 1024
#define BLOCK 256
#define GRID 2048
#define GROUPS_PER_BLOCK 1024   // n_vec / GRID = 2^21 / 2048
#define NWAVES 4                // BLOCK / 64

typedef float nfloat4 __attribute__((ext_vector_type(4)));
typedef int   nint4   __attribute__((ext_vector_type(4)));

__device__ __forceinline__ nfloat4 stage_compute(const float* s_map, float c, float d,
                                                 nint4 g, nfloat4 a, nfloat4 b) {
    nfloat4 o;
    o.x = s_map[g.x] + c * a.x + d * b.x;
    o.y = s_map[g.y] + c * a.y + d * b.y;
    o.z = s_map[g.z] + c * a.z + d * b.z;
    o.w = s_map[g.w] + c * a.w + d * b.w;
    return o;
}

__global__ __launch_bounds__(BLOCK, 4)
void Model_64364379898151_kernel(const int* __restrict__ x_gen,
                                 const float* __restrict__ x_clock,
                                 const float* __restrict__ x_tdp,
                                 const float* __restrict__ gen_map,
                                 const float* __restrict__ c_ptr,
                                 const float* __restrict__ d_ptr,
                                 float* __restrict__ out,
                                 int n_vec)  // number of vec4 groups
{
    // Per-wave private table: 4 waves x 4KB = 16KB LDS. Each wave stages the
    // whole 1024-entry map itself (gen_map is L2-resident after the first
    // block; the 4x redundant reads are L2 hits, not HBM traffic). This
    // removes __syncthreads() — and with it the compiler's mandatory
    // s_waitcnt vmcnt(0) lgkmcnt(0) drain that coupled all 4 waves.
    __shared__ float s_map_all[NWAVES * NUM_GENS];
    const int wave = threadIdx.x >> 6;
    const int lane = threadIdx.x & 63;
    float* s_map = &s_map_all[wave * NUM_GENS];

    const float c = c_ptr[0];
    const float d = d_ptr[0];

    const nfloat4* m4  = (const nfloat4*)gen_map;
    nfloat4*       sm4 = (nfloat4*)s_map;

    const nint4*   g4 = (const nint4*)  x_gen;
    const nfloat4* c4 = (const nfloat4*)x_clock;
    const nfloat4* t4 = (const nfloat4*)x_tdp;
    nfloat4*       o4 = (nfloat4*)      out;

    if (n_vec == GRID * GROUPS_PER_BLOCK) {
        // Fast path for N = 2^23.
        const int b       = blockIdx.x;
        const int logical = (b & 7) * (GRID / 8) + (b >> 3);
        const int base    = logical * GROUPS_PER_BLOCK + (int)threadIdx.x;

        const int j0 = base;
        const int j1 = base + 1 * BLOCK;
        const int j2 = base + 2 * BLOCK;
        const int j3 = base + 3 * BLOCK;

        // (1) Table loads FIRST — oldest in the vmem queue, so the ds_writes
        // below wait at vmcnt(12) and do NOT drain the streaming loads.
        nfloat4 m0 = m4[lane + 0 * 64];
        nfloat4 m1 = m4[lane + 1 * 64];
        nfloat4 m2 = m4[lane + 2 * 64];
        nfloat4 m3 = m4[lane + 3 * 64];

        // (2) Streaming loads interleaved per stage: with in-order vmem
        // returns, stage i is consumable after 3(i+1) returns.
        nint4   g0 = __builtin_nontemporal_load(g4 + j0);
        nfloat4 a0 = __builtin_nontemporal_load(c4 + j0);
        nfloat4 b0 = __builtin_nontemporal_load(t4 + j0);
        nint4   g1 = __builtin_nontemporal_load(g4 + j1);
        nfloat4 a1 = __builtin_nontemporal_load(c4 + j1);
        nfloat4 b1 = __builtin_nontemporal_load(t4 + j1);
        nint4   g2 = __builtin_nontemporal_load(g4 + j2);
        nfloat4 a2 = __builtin_nontemporal_load(c4 + j2);
        nfloat4 b2 = __builtin_nontemporal_load(t4 + j2);
        nint4   g3 = __builtin_nontemporal_load(g4 + j3);
        nfloat4 a3 = __builtin_nontemporal_load(c4 + j3);
        nfloat4 b3 = __builtin_nontemporal_load(t4 + j3);

        // (3) Stage this wave's private table (no barrier anywhere).
        sm4[lane + 0 * 64] = m0;
        sm4[lane + 1 * 64] = m1;
        sm4[lane + 2 * 64] = m2;
        sm4[lane + 3 * 64] = m3;

        // (4) Per-stage compute + nt-store as returns arrive; stores overlap
        // the remaining read returns of this and other waves.
        __builtin_nontemporal_store(stage_compute(s_map, c, d, g0, a0, b0), o4 + j0);
        __builtin_nontemporal_store(stage_compute(s_map, c, d, g1, a1, b1), o4 + j1);
        __builtin_nontemporal_store(stage_compute(s_map, c, d, g2, a2, b2), o4 + j2);
        __builtin_nontemporal_store(stage_compute(s_map, c, d, g3, a3, b3), o4 + j3);
    } else {
        // Generic grid-stride fallback (not taken for N = 2^23).
        nfloat4 m0 = m4[lane + 0 * 64];
        nfloat4 m1 = m4[lane + 1 * 64];
        nfloat4 m2 = m4[lane + 2 * 64];
        nfloat4 m3 = m4[lane + 3 * 64];
        sm4[lane + 0 * 64] = m0;
        sm4[lane + 1 * 64] = m1;
        sm4[lane + 2 * 64] = m2;
        sm4[lane + 3 * 64] = m3;

        const int idx    = blockIdx.x * BLOCK + threadIdx.x;
        const int stride = GRID * BLOCK;
        for (int i = idx; i < n_vec; i += stride) {
            nint4   g  = __builtin_nontemporal_load(g4 + i);
            nfloat4 cs = __builtin_nontemporal_load(c4 + i);
            nfloat4 td = __builtin_nontemporal_load(t4 + i);
            __builtin_nontemporal_store(stage_compute(s_map, c, d, g, cs, td), o4 + i);
        }
    }
}

extern "C" void kernel_launch(void* const* d_in, const int* in_sizes, int n_in,
                              void* d_out, int out_size, void* d_ws, size_t ws_size,
                              hipStream_t stream) {
    // setup_inputs() order:
    // 0: x_gen (int32, N)         1: x_ix (int32, N) -- unused
    // 2: x_max_clock_speed (f32)  3: x_max_tdp (f32)
    // 4: gen_map (f32, 1024)
    // 5: b (f32 scalar, unused)   6: c (f32 scalar)   7: d (f32 scalar)
    const int*   x_gen   = (const int*)  d_in[0];
    const float* x_clock = (const float*)d_in[2];
    const float* x_tdp   = (const float*)d_in[3];
    const float* gen_map = (const float*)d_in[4];
    const float* c_ptr   = (const float*)d_in[6];
    const float* d_ptr   = (const float*)d_in[7];
    float* out = (float*)d_out;

    const int n = in_sizes[0];          // 8388608
    const int n_vec = n / 4;            // 2^21 vec4 groups

    Model_64364379898151_kernel<<<GRID, BLOCK, 0, stream>>>(
        x_gen, x_clock, x_tdp, gen_map, c_ptr, d_ptr, out, n_vec);
}